// Round 1
// baseline (137.212 us; speedup 1.0000x reference)
//
#include <hip/hip_runtime.h>
#include <hip/hip_fp16.h>

// Problem constants (from reference):
//   x: [4,1,256,256] fp32, thetas: [180], positions: [256]
//   out: [4,1,180,256] fp32, T = ceil(sqrt(2)*256) = 363
#define NB   4
#define NA   180
#define NP   256
#define NH   256
#define NW   256
#define NT   363
#define GANG 3            // angles per block -> grid.x = 60, 240 blocks total
#define NSEG 4            // t-segments (threadIdx.y)
#define TSEG 91           // ceil(363/4)

// LDS image: rows -1..257 (259), cols -1..257 stored at alloc col c+1,
// padded to 262 halves/row (row stride 524 B -> bank step 3, conflict-free).
#define ROWS 259
#define COLS 262
#define IMG_HALFS (ROWS * COLS)        // 67858
#define IMG_BYTES (IMG_HALFS * 2)      // 135716 (4-byte multiple)
#define RED_BYTES (NP * NSEG * 4)      // 4096
#define SMEM_BYTES (IMG_BYTES + RED_BYTES)

extern "C" __global__ __launch_bounds__(1024)
void radon_fwd(const float* __restrict__ x,
               const float* __restrict__ thetas,
               const float* __restrict__ positions,
               float* __restrict__ out)
{
    extern __shared__ unsigned char smem[];
    __half* img = (__half*)smem;
    float*  red = (float*)(smem + IMG_BYTES);

    const int tid = threadIdx.x + (threadIdx.y << 8);   // 0..1023
    const int b   = blockIdx.y;
    const float* __restrict__ xb = x + b * (NH * NW);

    // --- 1) zero whole LDS image (interior + borders) ---
    unsigned int* img32 = (unsigned int*)img;
    for (int i = tid; i < IMG_HALFS / 2; i += 1024) img32[i] = 0u;
    __syncthreads();

    // --- 2) stage interior fp32 -> fp16 (coalesced float4 reads) ---
    const float4* src = (const float4*)xb;
    for (int i = tid; i < (NH * NW) / 4; i += 1024) {
        float4 v = src[i];
        int r = i >> 6;            // image row
        int c = (i & 63) << 2;     // image col of v.x
        int base = (r + 1) * COLS + (c + 1);
        img[base + 0] = __float2half(v.x);
        img[base + 1] = __float2half(v.y);
        img[base + 2] = __float2half(v.z);
        img[base + 3] = __float2half(v.w);
    }
    __syncthreads();

    // --- 3) ray integration ---
    const int   p   = threadIdx.x;
    const int   seg = threadIdx.y;
    const float s   = positions[p];
    const int   a0  = blockIdx.x * GANG;

    float accs[GANG];
    #pragma unroll
    for (int g = 0; g < GANG; ++g) {
        const float th = thetas[a0 + g];
        const float cv = cosf(th);
        const float sv = sinf(th);
        const float bx = 127.5f + s * cv;   // px = bx - t*sv
        const float by = 127.5f + s * sv;   // py = by + t*cv
        float acc = 0.f;
        const int t0 = seg * TSEG;
        const int t1 = min(NT, t0 + TSEG);
        for (int t = t0; t < t1; ++t) {
            const float tv = (float)t - 181.0f;   // (T-1)/2
            float px = fmaf(tv, -sv, bx);
            float py = fmaf(tv,  cv, by);
            // clamp into the zero border: exactly reproduces validity masks
            px = fminf(fmaxf(px, -1.0f), 256.0f);
            py = fminf(fmaxf(py, -1.0f), 256.0f);
            const float fx = floorf(px);
            const float fy = floorf(py);
            const float wx = px - fx;
            const float wy = py - fy;
            const int ix = (int)fx;               // in [-1, 256]
            const int iy = (int)fy;
            const int addr = (iy + 1) * COLS + (ix + 1);
            const float v00 = __half2float(img[addr]);
            const float v01 = __half2float(img[addr + 1]);
            const float v10 = __half2float(img[addr + COLS]);
            const float v11 = __half2float(img[addr + COLS + 1]);
            const float omx = 1.f - wx;
            const float omy = 1.f - wy;
            acc = fmaf(v00, omx * omy, acc);
            acc = fmaf(v01, wx  * omy, acc);
            acc = fmaf(v10, omx * wy , acc);
            acc = fmaf(v11, wx  * wy , acc);
        }
        accs[g] = acc;
    }

    // --- 4) cross-segment reduce (deterministic, via small LDS buffer) ---
    for (int g = 0; g < GANG; ++g) {
        __syncthreads();
        red[(seg << 8) + p] = accs[g];
        __syncthreads();
        if (seg == 0) {
            float r4 = red[p] + red[256 + p] + red[512 + p] + red[768 + p];
            out[b * (NA * NP) + (a0 + g) * NP + p] = r4;
        }
    }
}

extern "C" void kernel_launch(void* const* d_in, const int* in_sizes, int n_in,
                              void* d_out, int out_size, void* d_ws, size_t ws_size,
                              hipStream_t stream) {
    const float* x         = (const float*)d_in[0];
    const float* thetas    = (const float*)d_in[1];
    const float* positions = (const float*)d_in[2];
    float* out = (float*)d_out;

    // >64 KB dynamic LDS needs the attribute bump (idempotent, capture-safe).
    hipFuncSetAttribute((const void*)radon_fwd,
                        hipFuncAttributeMaxDynamicSharedMemorySize, SMEM_BYTES);

    dim3 grid(NA / GANG, NB);   // 60 x 4 = 240 blocks (~1 per CU)
    dim3 block(NP, NSEG);       // 256 x 4 = 1024 threads
    radon_fwd<<<grid, block, SMEM_BYTES, stream>>>(x, thetas, positions, out);
}

// Round 2
// 125.657 us; speedup vs baseline: 1.0920x; 1.0920x over previous
//
#include <hip/hip_runtime.h>
#include <hip/hip_fp16.h>

// Radon forward: x [4,1,256,256] f32, thetas[180], positions[256] -> out [4,1,180,256] f32
// T = ceil(sqrt(2)*256) = 363 samples per ray, bilinear taps, zero outside.
#define NB   4
#define NA   180
#define NP   256
#define NH   256
#define NW   256
#define NT   363
#define GANG 3            // angles per block -> grid = 60 x 4 = 240 blocks (~1/CU)
#define NSEG 4            // t-segments (threadIdx.y)
#define TSEG 91           // 4*91 = 364: the extra t=363 sample is >=182px from
                          // center (> circumscribed radius 181.7) -> falls fully in
                          // the zeroed border -> contributes exactly 0.

// LDS image, fp16, with zero border so no per-sample masking is needed:
//   alloc row = iy + 1  (interior rows 1..256; rows 0, 257, 258 zero)
//   alloc col = ix + 2  (interior cols 2..257; cols 0..1, 258..261 zero)
// Col offset 2 keeps interior __half2 staging stores 4B-aligned.
// Row stride 262 halves = 524 B -> bank step 3 (gcd(3,32)=1) -> conflict-free
// for vertical rays.
#define ROWS 259
#define COLS 262
#define IMG_HALFS (ROWS * COLS)        // 67858 (even)
#define IMG_DWORDS (IMG_HALFS / 2)     // 33929
#define IMG_BYTES (IMG_HALFS * 2)      // 135716
#define RED_BYTES (NP * NSEG * 4)      // 4096
#define SMEM_BYTES (IMG_BYTES + RED_BYTES)

extern "C" __global__ __launch_bounds__(1024)
void radon_fwd(const float* __restrict__ x,
               const float* __restrict__ thetas,
               const float* __restrict__ positions,
               float* __restrict__ out)
{
    extern __shared__ unsigned char smem[];
    __half*  img  = (__half*)smem;
    __half2* img2 = (__half2*)smem;
    float*   red  = (float*)(smem + IMG_BYTES);

    const int tid = threadIdx.x + (threadIdx.y << 8);   // 0..1023
    const int b   = blockIdx.y;
    const float* __restrict__ xb = x + b * (NH * NW);

    // --- 1) zero whole LDS image (border + interior) ---
    unsigned int* img32 = (unsigned int*)img;
    for (int i = tid; i < IMG_DWORDS; i += 1024) img32[i] = 0u;
    __syncthreads();

    // --- 2) stage interior f32 -> f16 as half2; consecutive lanes hit
    //        consecutive LDS dwords -> conflict-free writes ---
    const float2* src2 = (const float2*)xb;
    for (int j = tid; j < (NH * NW) / 2; j += 1024) {
        float2 v = src2[j];
        int r = j >> 7;          // image row
        int k = j & 127;         // half2 index within row (col = 2k)
        // alloc half2 index: ((r+1)*COLS + 2k + 2) / 2 = (r+1)*131 + k + 1
        img2[(r + 1) * 131 + k + 1] =
            __halves2half2(__float2half_rn(v.x), __float2half_rn(v.y));
    }
    __syncthreads();

    // --- 3) ray integration ---
    const int   p   = threadIdx.x;
    const int   seg = threadIdx.y;
    const float s   = positions[p];
    const int   a0  = blockIdx.x * GANG;
    const int   t0  = seg * TSEG;

    float accs[GANG];
    for (int g = 0; g < GANG; ++g) {
        const float th  = thetas[a0 + g];
        const float cv  = cosf(th);
        const float sv  = sinf(th);
        const float nsv = -sv;
        // px_alloc = (127.5 + 2) + s*cos - t*sin ; py_alloc = (127.5 + 1) + s*sin + t*cos
        const float bx2 = fmaf(s, cv, 129.5f);
        const float by1 = fmaf(s, sv, 128.5f);
        float acc = 0.f;
        #pragma unroll 4
        for (int t = 0; t < TSEG; ++t) {
            const float ft = (float)(t0 + t) - 181.0f;   // (T-1)/2
            float px = fmaf(ft, nsv, bx2);
            float py = fmaf(ft, cv,  by1);
            // clamp into zero border (exactly reproduces reference masking)
            px = __builtin_amdgcn_fmed3f(px, 1.0f, 258.0f);
            py = __builtin_amdgcn_fmed3f(py, 0.0f, 257.0f);
            const int   ix = (int)px;                    // trunc == floor (>=0)
            const int   iy = (int)py;
            const float wx = __builtin_amdgcn_fractf(px);
            const float wy = __builtin_amdgcn_fractf(py);
            const int a = iy * COLS + ix;                // half index
            const float v00 = __half2float(img[a]);
            const float v01 = __half2float(img[a + 1]);
            const float v10 = __half2float(img[a + COLS]);
            const float v11 = __half2float(img[a + COLS + 1]);
            const float omx = 1.f - wx;
            const float omy = 1.f - wy;
            acc = fmaf(v00, omx * omy, acc);
            acc = fmaf(v01, wx  * omy, acc);
            acc = fmaf(v10, omx * wy , acc);
            acc = fmaf(v11, wx  * wy , acc);
        }
        accs[g] = acc;
    }

    // --- 4) cross-segment reduce (deterministic) ---
    for (int g = 0; g < GANG; ++g) {
        __syncthreads();
        red[(seg << 8) + p] = accs[g];
        __syncthreads();
        if (seg == 0) {
            float r4 = red[p] + red[256 + p] + red[512 + p] + red[768 + p];
            out[b * (NA * NP) + (a0 + g) * NP + p] = r4;
        }
    }
}

extern "C" void kernel_launch(void* const* d_in, const int* in_sizes, int n_in,
                              void* d_out, int out_size, void* d_ws, size_t ws_size,
                              hipStream_t stream) {
    const float* x         = (const float*)d_in[0];
    const float* thetas    = (const float*)d_in[1];
    const float* positions = (const float*)d_in[2];
    float* out = (float*)d_out;

    hipFuncSetAttribute((const void*)radon_fwd,
                        hipFuncAttributeMaxDynamicSharedMemorySize, SMEM_BYTES);

    dim3 grid(NA / GANG, NB);   // 60 x 4 = 240 blocks
    dim3 block(NP, NSEG);       // 1024 threads
    radon_fwd<<<grid, block, SMEM_BYTES, stream>>>(x, thetas, positions, out);
}

// Round 3
// 125.589 us; speedup vs baseline: 1.0925x; 1.0005x over previous
//
#include <hip/hip_runtime.h>
#include <hip/hip_fp16.h>

// Radon forward: x [4,1,256,256] f32, thetas[180], positions[256] -> out [4,1,180,256] f32
// T = ceil(sqrt(2)*256) = 363 samples/ray, bilinear taps, zero outside.
#define NB   4
#define NA   180
#define NP   256
#define NH   256
#define NW   256
#define NT   363
#define GANG 3            // angles per block -> grid = 60 x 4 = 240 blocks (~1/CU)
#define NSEG 4            // t-segments (threadIdx.y)
#define TSEG 91           // 4*91=364; extra sample t=363 is >=182px from center
                          // (> circumscribed radius 181.7) -> lands in zero border -> +0.

// LDS image, fp16, zero border (no per-sample masking):
//   alloc row = iy + 1 (rows 0,257,258 zero), alloc col = ix + 2 (cols 0..1,258..261 zero)
// Row stride 262 halves = 131 dwords (odd -> decent bank spread for vertical rays).
#define ROWS 259
#define COLS 262
#define IMG_HALFS (ROWS * COLS)        // 67858
#define IMG_DWORDS (IMG_HALFS / 2)     // 33929
#define IMG_BYTES (IMG_HALFS * 2)      // 135716
#define RED_BYTES (NP * NSEG * 4)      // 4096
#define SMEM_BYTES (IMG_BYTES + RED_BYTES)

extern "C" __global__ __launch_bounds__(1024)
void radon_fwd(const float* __restrict__ x,
               const float* __restrict__ thetas,
               const float* __restrict__ positions,
               float* __restrict__ out)
{
    extern __shared__ unsigned char smem[];
    __half2*      img2  = (__half2*)smem;
    unsigned int* imgw  = (unsigned int*)smem;
    float*        red   = (float*)(smem + IMG_BYTES);

    const int tid = threadIdx.x + (threadIdx.y << 8);   // 0..1023
    const int b   = blockIdx.y;
    const float* __restrict__ xb = x + b * (NH * NW);

    // --- 1) zero whole LDS image (border + interior) ---
    for (int i = tid; i < IMG_DWORDS; i += 1024) imgw[i] = 0u;
    __syncthreads();

    // --- 2) stage interior f32 -> f16 as half2 (conflict-free writes) ---
    const float2* src2 = (const float2*)xb;
    for (int j = tid; j < (NH * NW) / 2; j += 1024) {
        float2 v = src2[j];
        int r = j >> 7;          // image row
        int k = j & 127;         // half2 index within row (col = 2k)
        // alloc half2 index: ((r+1)*COLS + 2k + 2)/2 = (r+1)*131 + k + 1
        img2[(r + 1) * 131 + k + 1] =
            __halves2half2(__float2half_rn(v.x), __float2half_rn(v.y));
    }
    __syncthreads();

    // --- 3) ray integration: 2 x ds_read2_b32 per sample ---
    const int   p   = threadIdx.x;
    const int   seg = threadIdx.y;
    const float s   = positions[p];
    const int   a0  = blockIdx.x * GANG;
    const int   t0  = seg * TSEG;

    float accs[GANG];
    for (int g = 0; g < GANG; ++g) {
        const float th  = thetas[a0 + g];
        const float cv  = cosf(th);
        const float sv  = sinf(th);
        const float nsv = -sv;
        // alloc-space ray: px = bx2 - t*sv (col offset +2), py = by1 + t*cv (row offset +1)
        const float bx2 = fmaf(s, cv, 129.5f);
        const float by1 = fmaf(s, sv, 128.5f);
        float acc = 0.f;
        #pragma unroll 4
        for (int t = 0; t < TSEG; ++t) {
            const float ftv = (float)(t0 + t) - 181.0f;   // (T-1)/2
            float px = fmaf(ftv, nsv, bx2);
            float py = fmaf(ftv, cv,  by1);
            // clamp into zero border (reproduces reference masking exactly)
            px = __builtin_amdgcn_fmed3f(px, 1.0f, 258.0f);
            py = __builtin_amdgcn_fmed3f(py, 0.0f, 257.0f);
            const float fx = floorf(px);
            const float fy = floorf(py);
            const float wx = px - fx;
            const float wy = py - fy;
            // half-index a = fy*262 + fx, exact in f32 (a < 2^17)
            const int a  = (int)fmaf(fy, 262.0f, fx);
            const int k  = a >> 1;
            const unsigned int sh = (a & 1) << 4;
            // two dword-pairs: row iy (k,k+1), row iy+1 (k+131,k+132)
            const unsigned int d0 = imgw[k];
            const unsigned int d1 = imgw[k + 1];
            const unsigned int d2 = imgw[k + 131];
            const unsigned int d3 = imgw[k + 132];
            // parity select: (d1:d0) >> sh -> (v00 | v01<<16), likewise row below
            unsigned int p0 =
                (unsigned int)(((((unsigned long long)d1) << 32) | d0) >> sh);
            unsigned int p1 =
                (unsigned int)(((((unsigned long long)d3) << 32) | d2) >> sh);
            const float2 f0 = __half22float2(*reinterpret_cast<__half2*>(&p0));
            const float2 f1 = __half22float2(*reinterpret_cast<__half2*>(&p1));
            // bilinear via 3 lerps
            const float h0 = fmaf(wx, f0.y - f0.x, f0.x);
            const float h1 = fmaf(wx, f1.y - f1.x, f1.x);
            acc = fmaf(wy, h1 - h0, acc + h0);
        }
        accs[g] = acc;
    }

    // --- 4) cross-segment reduce (deterministic) ---
    for (int g = 0; g < GANG; ++g) {
        __syncthreads();
        red[(seg << 8) + p] = accs[g];
        __syncthreads();
        if (seg == 0) {
            float r4 = red[p] + red[256 + p] + red[512 + p] + red[768 + p];
            out[b * (NA * NP) + (a0 + g) * NP + p] = r4;
        }
    }
}

extern "C" void kernel_launch(void* const* d_in, const int* in_sizes, int n_in,
                              void* d_out, int out_size, void* d_ws, size_t ws_size,
                              hipStream_t stream) {
    const float* x         = (const float*)d_in[0];
    const float* thetas    = (const float*)d_in[1];
    const float* positions = (const float*)d_in[2];
    float* out = (float*)d_out;

    hipFuncSetAttribute((const void*)radon_fwd,
                        hipFuncAttributeMaxDynamicSharedMemorySize, SMEM_BYTES);

    dim3 grid(NA / GANG, NB);   // 60 x 4 = 240 blocks
    dim3 block(NP, NSEG);       // 1024 threads
    radon_fwd<<<grid, block, SMEM_BYTES, stream>>>(x, thetas, positions, out);
}